// Round 4
// baseline (771.011 us; speedup 1.0000x reference)
//
#include <hip/hip_runtime.h>
#include <cstdint>
#include <cstddef>

#define B_N   8
#define C_N   256
#define H_N   128
#define W_N   128
#define S_N   16384          // H*W
#define CS_N  4194304        // C*S
#define NELEM 33554432       // B*C*S
#define EPS_F 1e-5f

typedef __attribute__((ext_vector_type(8))) short short8;   // 8 bf16 = 4 VGPR
typedef __attribute__((ext_vector_type(4))) float f32x4;

union PackB { uint32_t w[4]; uint4 u4; short8 s8; };

// round-to-nearest-even fp32 -> bf16 (bits), finite inputs
__device__ __forceinline__ uint32_t bf16_rne(float x) {
  const uint32_t u = __float_as_uint(x);
  return (u + 0x7FFFu + ((u >> 16) & 1u)) >> 16;
}
// pack (hi|lo) split of x into one word: hi = bf16(x), lo = bf16(x - hi)
__device__ __forceinline__ uint32_t splitpack(float x) {
  const uint32_t hi = bf16_rne(x);
  const float r = x - __uint_as_float(hi << 16);
  const uint32_t lo = bf16_rne(r);
  return (hi << 16) | lo;
}
// LDS word-index swizzle.
//  - XOR term is a multiple of 4 -> b128 reads stay 16B-contiguous.
//  - reads (lanes vary s&7 at fixed c0): 8 distinct 4-word groups -> 2-way min.
//  - writes (wave-uniform s per jj step, lanes = all 64 c): banks = c^const,
//    exactly 2 lanes/bank (free).  s>>4 term keeps distinct jj steps spread.
__device__ __forceinline__ int swz(int s, int c) {
  return (s * 64 + c) ^ ((((s & 7) ^ ((s >> 4) & 3)) << 2));
}

// ---------------------------------------------------------------------------
// Kernel 0: split W into bf16 hi/lo packed in per-lane MFMA fragment order.
// frag id f = ((tensor*8 + kf)*16 + mf)*2 + hl ; 1 KB per frag (64 lanes x 16B)
// lane's 8 bf16: o = mf*16 + (lane&15), c = kf*32 + (lane>>4)*8 + j
// ---------------------------------------------------------------------------
__global__ __launch_bounds__(256) void prep_w(
    const float* __restrict__ Wq, const float* __restrict__ Wk,
    uint4* __restrict__ wpk)
{
  const int gid = blockIdx.x * 256 + threadIdx.x;   // 32768 total
  const int lane = gid & 63;
  const int f = gid >> 6;                           // 0..511
  const int hl = f & 1;
  const int mf = (f >> 1) & 15;
  const int kf = (f >> 5) & 7;
  const int tensor = (f >> 8) & 1;
  const float* __restrict__ Wsrc = tensor ? Wk : Wq;

  const int o  = mf * 16 + (lane & 15);
  const int c0 = kf * 32 + ((lane >> 4) << 3);
  const float* src = Wsrc + (size_t)o * 256 + c0;
  const float4 x0 = *reinterpret_cast<const float4*>(src);
  const float4 x1 = *reinterpret_cast<const float4*>(src + 4);
  const float xs[8] = {x0.x, x0.y, x0.z, x0.w, x1.x, x1.y, x1.z, x1.w};

  uint32_t h[8];
#pragma unroll
  for (int e = 0; e < 8; ++e) {
    const uint32_t hi = bf16_rne(xs[e]);
    if (hl == 0) {
      h[e] = hi;
    } else {
      h[e] = bf16_rne(xs[e] - __uint_as_float(hi << 16));
    }
  }
  uint4 outw;
  outw.x = h[0] | (h[1] << 16);
  outw.y = h[2] | (h[3] << 16);
  outw.z = h[4] | (h[5] << 16);
  outw.w = h[6] | (h[7] << 16);
  wpk[(size_t)f * 64 + lane] = outw;
}

// ---------------------------------------------------------------------------
// Kernel 1: 1x1 conv as split-bf16 MFMA GEMM + fused GroupNorm partial stats.
// block tile M=256 (all o) x N=64 (one patch), K-step 64, 4 waves (64x64 each).
// A (W) fragments loaded straight from pre-packed L2-resident wpk.
// B (X) split in-kernel -> LDS [s][c] packed (hi|lo) words, swizzled,
// double-buffered; Y ~= Ahi*Bhi + Ahi*Blo + Alo*Bhi (fp32 accum in MFMA).
// Epilogue: per-(tensor,b,group) Sum/SumSq partials -> global atomicAdd.
// Output layout: tensor 0 (qf=d_out) standard s ; tensor 1 (kf) patch-major.
// ---------------------------------------------------------------------------
__global__ __launch_bounds__(256) void conv_mfma(
    const float* __restrict__ x_low, const float* __restrict__ x_high,
    const uint4* __restrict__ wpk,
    float* __restrict__ qf, float* __restrict__ kf,
    float2* __restrict__ stats)
{
  const int t = threadIdx.x;
  const int lane = t & 63;
  const int w = t >> 6;                 // wave 0..3
  // XCD-contiguous tile swizzle: xcd (= bx&7 since gridDim.x=256, by*256%8==0)
  // gets 32 consecutive s-tiles -> w-adjacent patches share its L2 lines.
  const int tile = ((blockIdx.x & 7) << 5) | (blockIdx.x >> 3);
  const int bz = blockIdx.y;            // 0..15
  const int tensor = bz >> 3;
  const int b = bz & 7;

  const float* __restrict__ X = tensor ? x_high : x_low;
  float* __restrict__ Y = tensor ? kf : qf;
  const short8* __restrict__ wpkS = reinterpret_cast<const short8*>(wpk);

  const size_t xbase = (size_t)b * CS_N;
  const int s0 = tile * 64;

  __shared__ uint32_t xb[2][4096];      // [s(64)][c(64)] packed words, swizzled

  // ---- staging: thread = (c = lane, s-quarter = wave) ----
  const int cl = lane;                  // c_local 0..63
  const int sq = w;                     // s-quarter 0..3 (wave-uniform)
  int offA, offB;                       // element offsets of the two 8-f runs
  if (tensor) {
    const int rA = 2 * sq, rB = 2 * sq + 1;        // patch rows
    const int pb = ((tile >> 4) << 3) * W_N + ((tile & 15) << 3);
    offA = pb + rA * W_N;
    offB = pb + rB * W_N;
  } else {
    offA = s0 + sq * 16;
    offB = offA + 8;
  }
  const float* __restrict__ Xb = X + xbase;

  f32x4 acc[4][4] = {};

  // convert+write one staged register set into buffer nb
  auto stage_write = [&](const float4& A0, const float4& A1,
                         const float4& B0, const float4& B1, int nb) {
    const float v[16] = {A0.x, A0.y, A0.z, A0.w, A1.x, A1.y, A1.z, A1.w,
                         B0.x, B0.y, B0.z, B0.w, B1.x, B1.y, B1.z, B1.w};
#pragma unroll
    for (int jj = 0; jj < 16; ++jj) {
      const int sl = sq * 16 + jj;
      xb[nb][swz(sl, cl)] = splitpack(v[jj]);
    }
  };

  // prologue: stage kt=0 into buffer 0
  {
    const float* p = Xb + (size_t)cl * S_N;
    const float4 A0 = *reinterpret_cast<const float4*>(p + offA);
    const float4 A1 = *reinterpret_cast<const float4*>(p + offA + 4);
    const float4 B0 = *reinterpret_cast<const float4*>(p + offB);
    const float4 B1 = *reinterpret_cast<const float4*>(p + offB + 4);
    stage_write(A0, A1, B0, B1, 0);
  }

  for (int kt = 0; kt < 4; ++kt) {
    const int cur = kt & 1;
    __syncthreads();

    // issue next tile's global loads early (latency hides under MFMA)
    float4 nA0, nA1, nB0, nB1;
    if (kt < 3) {
      const float* p = Xb + (size_t)((kt + 1) * 64 + cl) * S_N;
      nA0 = *reinterpret_cast<const float4*>(p + offA);
      nA1 = *reinterpret_cast<const float4*>(p + offA + 4);
      nB0 = *reinterpret_cast<const float4*>(p + offB);
      nB1 = *reinterpret_cast<const float4*>(p + offB + 4);
    }

    // ---- compute 2 K32 steps from buf[cur] ----
#pragma unroll
    for (int ks = 0; ks < 2; ++ks) {
      const int kfrag = kt * 2 + ks;
      const int fbase = ((tensor * 8 + kfrag) * 16 + w * 4) * 2;
      short8 a_hi[4], a_lo[4];
#pragma unroll
      for (int mf = 0; mf < 4; ++mf) {
        a_hi[mf] = wpkS[(size_t)(fbase + mf * 2) * 64 + lane];
        a_lo[mf] = wpkS[(size_t)(fbase + mf * 2 + 1) * 64 + lane];
      }
      short8 b_hi[4], b_lo[4];
      const int c0 = ks * 32 + ((lane >> 4) << 3);
#pragma unroll
      for (int nf = 0; nf < 4; ++nf) {
        const int sl = nf * 16 + (lane & 15);
        const int base1 = swz(sl, c0);
        const int base2 = swz(sl, c0 + 4);
        const uint4 u = *reinterpret_cast<const uint4*>(&xb[cur][base1]);
        const uint4 v = *reinterpret_cast<const uint4*>(&xb[cur][base2]);
        PackB ph, pl;
        ph.w[0] = __builtin_amdgcn_perm(u.y, u.x, 0x07060302u);
        ph.w[1] = __builtin_amdgcn_perm(u.w, u.z, 0x07060302u);
        ph.w[2] = __builtin_amdgcn_perm(v.y, v.x, 0x07060302u);
        ph.w[3] = __builtin_amdgcn_perm(v.w, v.z, 0x07060302u);
        pl.w[0] = __builtin_amdgcn_perm(u.y, u.x, 0x05040100u);
        pl.w[1] = __builtin_amdgcn_perm(u.w, u.z, 0x05040100u);
        pl.w[2] = __builtin_amdgcn_perm(v.y, v.x, 0x05040100u);
        pl.w[3] = __builtin_amdgcn_perm(v.w, v.z, 0x05040100u);
        b_hi[nf] = ph.s8;
        b_lo[nf] = pl.s8;
      }
#pragma unroll
      for (int mf = 0; mf < 4; ++mf)
#pragma unroll
        for (int nf = 0; nf < 4; ++nf) {
          acc[mf][nf] = __builtin_amdgcn_mfma_f32_16x16x32_bf16(
              a_hi[mf], b_hi[nf], acc[mf][nf], 0, 0, 0);
          acc[mf][nf] = __builtin_amdgcn_mfma_f32_16x16x32_bf16(
              a_hi[mf], b_lo[nf], acc[mf][nf], 0, 0, 0);
          acc[mf][nf] = __builtin_amdgcn_mfma_f32_16x16x32_bf16(
              a_lo[mf], b_hi[nf], acc[mf][nf], 0, 0, 0);
        }
    }

    if (kt < 3) stage_write(nA0, nA1, nB0, nB1, cur ^ 1);
  }

  // ---- epilogue: D col = lane&15 (s), row = (lane>>4)*4 + reg (o) ----
  const int orow = w * 64 + ((lane >> 4) << 2);
  const int scol = s0 + (lane & 15);
#pragma unroll
  for (int mf = 0; mf < 4; ++mf)
#pragma unroll
    for (int nf = 0; nf < 4; ++nf) {
      const int o = orow + mf * 16;
      const int s = scol + nf * 16;
#pragma unroll
      for (int r = 0; r < 4; ++r)
        Y[xbase + (size_t)(o + r) * S_N + s] = acc[mf][nf][r];
    }

  // ---- fused GroupNorm partial stats ----
  // thread's o-range per mf lies in group g = w*8 + mf*2 + (lane>>5)
  float s1g[4], s2g[4];
#pragma unroll
  for (int mf = 0; mf < 4; ++mf) {
    float a = 0.0f, q = 0.0f;
#pragma unroll
    for (int nf = 0; nf < 4; ++nf)
#pragma unroll
      for (int r = 0; r < 4; ++r) {
        const float v = acc[mf][nf][r];
        a += v;
        q = fmaf(v, v, q);
      }
    s1g[mf] = a; s2g[mf] = q;
  }
  // butterfly within 32-lane halves (hi = lane>>5 is invariant under off<=16)
#pragma unroll
  for (int off = 16; off >= 1; off >>= 1) {
#pragma unroll
    for (int mf = 0; mf < 4; ++mf) {
      s1g[mf] += __shfl_xor(s1g[mf], off);
      s2g[mf] += __shfl_xor(s2g[mf], off);
    }
  }
  if ((lane & 31) == 0) {
    const int hi = lane >> 5;
    float2* st = stats + (tensor * 256 + b * 32);
#pragma unroll
    for (int mf = 0; mf < 4; ++mf) {
      const int g = w * 8 + mf * 2 + hi;
      atomicAdd(&st[g].x, s1g[mf]);
      atomicAdd(&st[g].y, s2g[mf]);
    }
  }
}

// ---------------------------------------------------------------------------
// Kernel 3: per-patch attention.  Identical structure to the verified
// round-2/3 kernel, except stats now arrive as raw (Sum, SumSq) and
// mean/rsqrt are computed inline.
// ---------------------------------------------------------------------------
__global__ __launch_bounds__(256) void attn_kernel(
    const float* __restrict__ x_low,
    const float* __restrict__ gq, const float* __restrict__ bq,
    const float* __restrict__ gk, const float* __restrict__ bk,
    const float* __restrict__ qf, const float* __restrict__ kf,
    const float2* __restrict__ stats, float* __restrict__ out)
{
  const int n = ((blockIdx.x & 7) << 8) | (blockIdx.x >> 3);
  const int b = n >> 8;
  const int nl = n & 255;
  const int h0 = (nl >> 4) << 3, w0 = (nl & 15) << 3;
  const int t = threadIdx.x;
  const int tx = t & 15, ty = t >> 4;
  const int p = t & 63;
  const int ci = t >> 6;

  __shared__ float q_ch[64][68];
  __shared__ float k_ch[64][68];
  __shared__ float s_mat[64][68];
  __shared__ float red[4][64];
  __shared__ float rowstat[2][64];

  const int lc = t >> 2;
  const int lp = (t & 3) << 4;

  const size_t kbase = (size_t)b * CS_N + ((size_t)nl << 6) + lp;
  const size_t pixoff =
      (size_t)b * CS_N + (size_t)(h0 + (p >> 3)) * W_N + (w0 + (p & 7));

  const float inv_n = 1.0f / 131072.0f;

  float accs[4][4];
#pragma unroll
  for (int i = 0; i < 4; ++i)
#pragma unroll
    for (int j = 0; j < 4; ++j) accs[i][j] = 0.0f;

  for (int chunk = 0; chunk < 4; ++chunk) {
    __syncthreads();
    {
      const int c = (chunk << 6) + lc;
      const float2 sk = stats[256 + (b << 5) + (c >> 3)];
      const float mk = sk.x * inv_n;
      const float rk = rsqrtf(fmaf(-mk, mk, sk.y * inv_n) + EPS_F);
      const float ksc = gk[c] * rk;
      const float ksh = bk[c] - mk * ksc;
      const float4* src = reinterpret_cast<const float4*>(kf + kbase + (size_t)c * S_N);
      const float4 v0 = src[0], v1 = src[1], v2 = src[2], v3 = src[3];
      float4* dst = reinterpret_cast<float4*>(&k_ch[lc][lp]);
      dst[0] = make_float4(fmaf(v0.x, ksc, ksh), fmaf(v0.y, ksc, ksh),
                           fmaf(v0.z, ksc, ksh), fmaf(v0.w, ksc, ksh));
      dst[1] = make_float4(fmaf(v1.x, ksc, ksh), fmaf(v1.y, ksc, ksh),
                           fmaf(v1.z, ksc, ksh), fmaf(v1.w, ksc, ksh));
      dst[2] = make_float4(fmaf(v2.x, ksc, ksh), fmaf(v2.y, ksc, ksh),
                           fmaf(v2.z, ksc, ksh), fmaf(v2.w, ksc, ksh));
      dst[3] = make_float4(fmaf(v3.x, ksc, ksh), fmaf(v3.y, ksc, ksh),
                           fmaf(v3.z, ksc, ksh), fmaf(v3.w, ksc, ksh));
    }
    for (int cl = ci; cl < 64; cl += 4) {
      const int c = (chunk << 6) + cl;
      const float2 sq = stats[(b << 5) + (c >> 3)];
      const float mq = sq.x * inv_n;
      const float rq = rsqrtf(fmaf(-mq, mq, sq.y * inv_n) + EPS_F);
      const float qsc = gq[c] * rq * 0.0625f;
      const float qsh = (bq[c] - mq * gq[c] * rq) * 0.0625f;
      q_ch[cl][p] = fmaf(qf[pixoff + (size_t)c * S_N], qsc, qsh);
    }
    __syncthreads();
#pragma unroll 4
    for (int c = 0; c < 64; ++c) {
      const float4 qv = *reinterpret_cast<const float4*>(&q_ch[c][ty * 4]);
      const float4 kv = *reinterpret_cast<const float4*>(&k_ch[c][tx * 4]);
      const float qa[4] = {qv.x, qv.y, qv.z, qv.w};
      const float ka[4] = {kv.x, kv.y, kv.z, kv.w};
#pragma unroll
      for (int i = 0; i < 4; ++i)
#pragma unroll
        for (int j = 0; j < 4; ++j) accs[i][j] = fmaf(qa[i], ka[j], accs[i][j]);
    }
  }
#pragma unroll
  for (int j = 0; j < 4; ++j)
    *reinterpret_cast<float4*>(&s_mat[tx * 4 + j][ty * 4]) =
        make_float4(accs[0][j], accs[1][j], accs[2][j], accs[3][j]);
  __syncthreads();

  {
    float m = -3.0e38f;
#pragma unroll
    for (int rr = 0; rr < 16; ++rr) m = fmaxf(m, s_mat[ci * 16 + rr][p]);
    red[ci][p] = m;
    __syncthreads();
    if (t < 64)
      rowstat[0][t] = fmaxf(fmaxf(red[0][t], red[1][t]), fmaxf(red[2][t], red[3][t]));
    __syncthreads();
    const float rm = rowstat[0][p];
    float sum = 0.0f;
#pragma unroll
    for (int rr = 0; rr < 16; ++rr) {
      const float e = __expf(s_mat[ci * 16 + rr][p] - rm);
      s_mat[ci * 16 + rr][p] = e;
      sum += e;
    }
    red[ci][p] = sum;
    __syncthreads();
    if (t < 64) rowstat[1][t] = red[0][t] + red[1][t] + red[2][t] + red[3][t];
    __syncthreads();
  }
  const float rinv = 1.0f / rowstat[1][p];

  for (int chunk = 0; chunk < 4; ++chunk) {
    __syncthreads();
    {
      const int c = (chunk << 6) + lc;
      const float2 sk = stats[256 + (b << 5) + (c >> 3)];
      const float mk = sk.x * inv_n;
      const float rk = rsqrtf(fmaf(-mk, mk, sk.y * inv_n) + EPS_F);
      const float ksc = gk[c] * rk;
      const float ksh = bk[c] - mk * ksc;
      const float4* src = reinterpret_cast<const float4*>(kf + kbase + (size_t)c * S_N);
      const float4 v0 = src[0], v1 = src[1], v2 = src[2], v3 = src[3];
      const float vals[16] = {v0.x, v0.y, v0.z, v0.w, v1.x, v1.y, v1.z, v1.w,
                              v2.x, v2.y, v2.z, v2.w, v3.x, v3.y, v3.z, v3.w};
#pragma unroll
      for (int u = 0; u < 16; ++u) k_ch[lp + u][lc] = fmaf(vals[u], ksc, ksh);
    }
    __syncthreads();
    float accp[4][4];
#pragma unroll
    for (int i = 0; i < 4; ++i)
#pragma unroll
      for (int j = 0; j < 4; ++j) accp[i][j] = 0.0f;
#pragma unroll 4
    for (int r = 0; r < 64; ++r) {
      const float4 pv = *reinterpret_cast<const float4*>(&s_mat[r][ty * 4]);
      const float4 kv = *reinterpret_cast<const float4*>(&k_ch[r][tx * 4]);
      const float pa[4] = {pv.x, pv.y, pv.z, pv.w};
      const float ka[4] = {kv.x, kv.y, kv.z, kv.w};
#pragma unroll
      for (int i = 0; i < 4; ++i)
#pragma unroll
        for (int j = 0; j < 4; ++j) accp[i][j] = fmaf(pa[i], ka[j], accp[i][j]);
    }
#pragma unroll
    for (int i = 0; i < 4; ++i)
      *reinterpret_cast<float4*>(&q_ch[ty * 4 + i][tx * 4]) =
          make_float4(accp[i][0], accp[i][1], accp[i][2], accp[i][3]);
    __syncthreads();
    for (int cl = ci; cl < 64; cl += 4) {
      const size_t a = pixoff + (size_t)((chunk << 6) + cl) * S_N;
      out[a] = fmaf(q_ch[p][cl], rinv, x_low[a]);
    }
  }
}

// ---------------------------------------------------------------------------
extern "C" void kernel_launch(void* const* d_in, const int* in_sizes, int n_in,
                              void* d_out, int out_size, void* d_ws, size_t ws_size,
                              hipStream_t stream)
{
  const float* x_low  = (const float*)d_in[0];
  const float* x_high = (const float*)d_in[1];
  const float* Wq     = (const float*)d_in[2];
  const float* gq     = (const float*)d_in[3];
  const float* bq     = (const float*)d_in[4];
  const float* Wk     = (const float*)d_in[5];
  const float* gk     = (const float*)d_in[6];
  const float* bk     = (const float*)d_in[7];
  float* out = (float*)d_out;

  float* qf = out;                    // standard layout (attn overwrites same addrs)
  float* kf = (float*)d_ws;           // patch-major layout, 128 MiB
  float2* stats = (float2*)((char*)d_ws + (size_t)NELEM * 4);      // 4 KB (Sum,SumSq)
  uint4* wpk = (uint4*)((char*)d_ws + (size_t)NELEM * 4 + 4096);   // 512 KB

  hipMemsetAsync(stats, 0, 512 * sizeof(float2), stream);
  hipLaunchKernelGGL(prep_w, dim3(128), dim3(256), 0, stream, Wq, Wk, wpk);
  hipLaunchKernelGGL(conv_mfma, dim3(256, 16), dim3(256), 0, stream,
                     x_low, x_high, wpk, qf, kf, stats);
  hipLaunchKernelGGL(attn_kernel, dim3(2048), dim3(256), 0, stream,
                     x_low, gq, bq, gk, bk, qf, kf, stats, out);
}